// Round 1
// baseline (787.876 us; speedup 1.0000x reference)
//
#include <hip/hip_runtime.h>
#include <hip/hip_bf16.h>

// GCN 2-layer: out = log_softmax(GCN2(relu(GCN1(x))))
// GCNConv: h=xW; agg = D^-1/2 (A+I) D^-1/2 h + b  (aggregate src->dst)
//
// Strategy: build dst-sorted CSR once per launch (hist + scan + scatter),
// then gather-aggregate with one wave per node (no fp32 atomics).
// fp32 everywhere (round 1: correctness anchor).

#define N_NODES 100000
#define F_IN 256
#define F_MID 128
#define F_OUT 64

// ---------------- sort pipeline ----------------

__global__ void hist_kernel(const int* __restrict__ dst, int* __restrict__ cnt, int E) {
    int e = blockIdx.x * 256 + threadIdx.x;
    if (e < E) atomicAdd(&cnt[dst[e]], 1);
}

__global__ void scanA_kernel(const int* __restrict__ cnt, int* __restrict__ rs,
                             int* __restrict__ bsum, int n) {
    __shared__ int s[256];
    int i = blockIdx.x * 256 + threadIdx.x;
    int v = (i < n) ? cnt[i] : 0;
    s[threadIdx.x] = v;
    __syncthreads();
    for (int off = 1; off < 256; off <<= 1) {
        int t = (threadIdx.x >= off) ? s[threadIdx.x - off] : 0;
        __syncthreads();
        s[threadIdx.x] += t;
        __syncthreads();
    }
    if (i < n) rs[i] = s[threadIdx.x] - v;   // exclusive within block
    if (threadIdx.x == 255) bsum[blockIdx.x] = s[255];
}

__global__ void scanB_kernel(const int* __restrict__ bsum, int* __restrict__ boff, int nb) {
    __shared__ int s[512];
    int tid = threadIdx.x;
    int v = (tid < nb) ? bsum[tid] : 0;
    s[tid] = v;
    __syncthreads();
    for (int off = 1; off < 512; off <<= 1) {
        int t = (tid >= off) ? s[tid - off] : 0;
        __syncthreads();
        s[tid] += t;
        __syncthreads();
    }
    if (tid < nb) boff[tid] = s[tid] - v;    // exclusive
}

// finalize row_start (+block offset), init cursor, compute dinv = 1/sqrt(deg+1)
__global__ void scanC_kernel(int* __restrict__ rs, const int* __restrict__ boff,
                             int* __restrict__ cursor, const int* __restrict__ cnt,
                             float* __restrict__ dinv, int n) {
    int i = blockIdx.x * 256 + threadIdx.x;
    if (i < n) {
        int v = rs[i] + boff[blockIdx.x];
        rs[i] = v;
        cursor[i] = v;
        dinv[i] = 1.0f / sqrtf((float)cnt[i] + 1.0f);
    }
}

__global__ void scatter_kernel(const int* __restrict__ src, const int* __restrict__ dst,
                               int* __restrict__ cursor, int* __restrict__ ssrc, int E) {
    int e = blockIdx.x * 256 + threadIdx.x;
    if (e < E) {
        int d = dst[e];
        int pos = atomicAdd(&cursor[d], 1);
        ssrc[pos] = src[e];
    }
}

// ---------------- GEMM (fp32, tiled) ----------------
// C[M x BN] = A[M x K] @ B[K x BN].  BM=64, BK=32, 256 threads,
// thread tile 4 x TN, TCOLS = BN/TN = 16, TROWS = 16.

template <int BN, int TN>
__global__ __launch_bounds__(256)
void gemm_kernel(const float* __restrict__ A, const float* __restrict__ B,
                 float* __restrict__ C, int M, int K) {
    constexpr int BM = 64, BK = 32;
    constexpr int TCOLS = BN / TN;   // 16
    __shared__ float As[BK][BM + 4]; // transposed: As[k][m]
    __shared__ float Bs[BK][BN + 4];
    int tid = threadIdx.x;
    int tcol = tid % TCOLS, trow = tid / TCOLS;
    int m0 = blockIdx.x * BM;
    float acc[4][TN];
#pragma unroll
    for (int i = 0; i < 4; ++i)
#pragma unroll
        for (int j = 0; j < TN; ++j) acc[i][j] = 0.0f;

    for (int k0 = 0; k0 < K; k0 += BK) {
        // A tile: 64 rows x 32 k = 512 float4, 2 per thread
        {
            int r = tid / 8, kq = tid % 8;
#pragma unroll
            for (int rr = r; rr < BM; rr += 32) {
                int grow = m0 + rr;
                float4 v = make_float4(0.f, 0.f, 0.f, 0.f);
                if (grow < M) v = *(const float4*)&A[(size_t)grow * K + k0 + kq * 4];
                As[kq * 4 + 0][rr] = v.x;
                As[kq * 4 + 1][rr] = v.y;
                As[kq * 4 + 2][rr] = v.z;
                As[kq * 4 + 3][rr] = v.w;
            }
        }
        // B tile: BK x BN
        {
            constexpr int F4_PER_ROW = BN / 4;
            constexpr int ROWS_PER_PASS = 256 / F4_PER_ROW;
            int r = tid / F4_PER_ROW, c4 = tid % F4_PER_ROW;
#pragma unroll
            for (int rr = r; rr < BK; rr += ROWS_PER_PASS) {
                float4 v = *(const float4*)&B[(size_t)(k0 + rr) * BN + c4 * 4];
                *(float4*)&Bs[rr][c4 * 4] = v;
            }
        }
        __syncthreads();
#pragma unroll
        for (int kk = 0; kk < BK; ++kk) {
            float a[4], b[TN];
            float4 av = *(const float4*)&As[kk][trow * 4];
            a[0] = av.x; a[1] = av.y; a[2] = av.z; a[3] = av.w;
#pragma unroll
            for (int j = 0; j < TN; j += 4) {
                float4 bv = *(const float4*)&Bs[kk][tcol * TN + j];
                b[j] = bv.x; b[j + 1] = bv.y; b[j + 2] = bv.z; b[j + 3] = bv.w;
            }
#pragma unroll
            for (int i = 0; i < 4; ++i)
#pragma unroll
                for (int j = 0; j < TN; ++j) acc[i][j] += a[i] * b[j];
        }
        __syncthreads();
    }
#pragma unroll
    for (int i = 0; i < 4; ++i) {
        int grow = m0 + trow * 4 + i;
        if (grow < M) {
#pragma unroll
            for (int j = 0; j < TN; j += 4) {
                float4 v = make_float4(acc[i][j], acc[i][j + 1], acc[i][j + 2], acc[i][j + 3]);
                *(float4*)&C[(size_t)grow * BN + tcol * TN + j] = v;
            }
        }
    }
}

// ---------------- aggregation ----------------
// one wave per node; 128 feats -> float2 per lane

__global__ __launch_bounds__(256)
void agg1_kernel(const float* __restrict__ h, const int* __restrict__ rs,
                 const int* __restrict__ cnt, const int* __restrict__ ssrc,
                 const float* __restrict__ dinv, const float* __restrict__ bias,
                 float* __restrict__ out, int n) {
    int w = threadIdx.x >> 6, l = threadIdx.x & 63;
    int node = blockIdx.x * 4 + w;
    if (node >= n) return;
    int start = rs[node], c = cnt[node];
    float dn = dinv[node];
    const float2* hv = (const float2*)h;
    float ax = 0.f, ay = 0.f;
    for (int j = 0; j < c; ++j) {
        int s = ssrc[start + j];
        float ws = dinv[s];
        float2 v = hv[(size_t)s * 64 + l];
        ax += ws * v.x;
        ay += ws * v.y;
    }
    float2 hs = hv[(size_t)node * 64 + l];
    float2 b = ((const float2*)bias)[l];
    float ox = dn * ax + dn * dn * hs.x + b.x;
    float oy = dn * ay + dn * dn * hs.y + b.y;
    ox = fmaxf(ox, 0.f);
    oy = fmaxf(oy, 0.f);
    ((float2*)out)[(size_t)node * 64 + l] = make_float2(ox, oy);
}

// 64 feats -> 1 per lane, fused bias + log_softmax (wave reduction)
__global__ __launch_bounds__(256)
void agg2_kernel(const float* __restrict__ h, const int* __restrict__ rs,
                 const int* __restrict__ cnt, const int* __restrict__ ssrc,
                 const float* __restrict__ dinv, const float* __restrict__ bias,
                 float* __restrict__ out, int n) {
    int w = threadIdx.x >> 6, l = threadIdx.x & 63;
    int node = blockIdx.x * 4 + w;
    if (node >= n) return;
    int start = rs[node], c = cnt[node];
    float dn = dinv[node];
    float acc = 0.f;
    for (int j = 0; j < c; ++j) {
        int s = ssrc[start + j];
        acc += dinv[s] * h[(size_t)s * 64 + l];
    }
    float v = dn * acc + dn * dn * h[(size_t)node * 64 + l] + bias[l];
    // log_softmax over the 64 lanes
    float m = v;
    for (int off = 32; off; off >>= 1) m = fmaxf(m, __shfl_xor(m, off));
    float e = expf(v - m);
    float ssum = e;
    for (int off = 32; off; off >>= 1) ssum += __shfl_xor(ssum, off);
    out[(size_t)node * 64 + l] = v - m - logf(ssum);
}

// ---------------- launch ----------------

extern "C" void kernel_launch(void* const* d_in, const int* in_sizes, int n_in,
                              void* d_out, int out_size, void* d_ws, size_t ws_size,
                              hipStream_t stream) {
    const float* x  = (const float*)d_in[0];
    const int*   ei = (const int*)d_in[1];
    const float* W1 = (const float*)d_in[2];
    const float* b1 = (const float*)d_in[3];
    const float* W2 = (const float*)d_in[4];
    const float* b2 = (const float*)d_in[5];
    float* out = (float*)d_out;

    const int N = N_NODES;
    const int E = in_sizes[1] / 2;
    const int* src = ei;
    const int* dst = ei + E;

    // workspace carve-up (256B aligned)
    char* ws = (char*)d_ws;
    size_t off = 0;
    auto alloc = [&](size_t bytes) {
        char* p = ws + off;
        off = (off + bytes + 255) & ~(size_t)255;
        return p;
    };
    int*   cnt    = (int*)alloc(N * 4);
    int*   rs     = (int*)alloc(N * 4);
    int*   cursor = (int*)alloc(N * 4);
    float* dinv   = (float*)alloc(N * 4);
    int*   bsum   = (int*)alloc(512 * 4);
    int*   boff   = (int*)alloc(512 * 4);
    int*   ssrc   = (int*)alloc((size_t)E * 4);
    float* h1     = (float*)alloc((size_t)N * F_MID * 4);
    float* h1a    = (float*)alloc((size_t)N * F_MID * 4);
    float* h2     = h1;  // alias: h1 dead after agg1

    const int nScanBlocks = (N + 255) / 256;        // 391
    const int nEdgeBlocks = (E + 255) / 256;        // 6250
    const int nAggBlocks  = (N + 3) / 4;            // 25000
    const int nGemmBlocks = (N + 63) / 64;          // 1563

    hipMemsetAsync(cnt, 0, N * 4, stream);

    hist_kernel<<<nEdgeBlocks, 256, 0, stream>>>(dst, cnt, E);
    scanA_kernel<<<nScanBlocks, 256, 0, stream>>>(cnt, rs, bsum, N);
    scanB_kernel<<<1, 512, 0, stream>>>(bsum, boff, nScanBlocks);
    scanC_kernel<<<nScanBlocks, 256, 0, stream>>>(rs, boff, cursor, cnt, dinv, N);
    scatter_kernel<<<nEdgeBlocks, 256, 0, stream>>>(src, dst, cursor, ssrc, E);

    gemm_kernel<F_MID, 8><<<nGemmBlocks, 256, 0, stream>>>(x, W1, h1, N, F_IN);
    agg1_kernel<<<nAggBlocks, 256, 0, stream>>>(h1, rs, cnt, ssrc, dinv, b1, h1a, N);
    gemm_kernel<F_OUT, 4><<<nGemmBlocks, 256, 0, stream>>>(h1a, W2, h2, N, F_MID);
    agg2_kernel<<<nAggBlocks, 256, 0, stream>>>(h2, rs, cnt, ssrc, dinv, b2, out, N);
}

// Round 2
// 588.346 us; speedup vs baseline: 1.3391x; 1.3391x over previous
//
#include <hip/hip_runtime.h>
#include <hip/hip_bf16.h>

// GCN 2-layer: out = log_softmax(GCN2(relu(GCN1(x))))
// Round 2: bf16 interfaces + MFMA GEMMs + packed (src,w) edge list with
// shfl-broadcast gather loops. fp32 accumulation everywhere.

#define N_NODES 100000
#define F_IN 256
#define F_MID 128
#define F_OUT 64

typedef __attribute__((ext_vector_type(8))) short short8;
typedef __attribute__((ext_vector_type(4))) float f32x4;

__device__ inline ushort bf16_rne(float f) {
    uint u = __float_as_uint(f);
    u += 0x7FFF + ((u >> 16) & 1);
    return (ushort)(u >> 16);
}
__device__ inline float bf16_f(ushort h) { return __uint_as_float(((uint)h) << 16); }

// ---------------- sort pipeline ----------------

__global__ void hist_kernel(const int* __restrict__ dst, int* __restrict__ cnt, int E) {
    int e = blockIdx.x * 256 + threadIdx.x;
    if (e < E) atomicAdd(&cnt[dst[e]], 1);
}

__global__ void scanA_kernel(const int* __restrict__ cnt, int* __restrict__ rs,
                             int* __restrict__ bsum, int n) {
    __shared__ int s[256];
    int i = blockIdx.x * 256 + threadIdx.x;
    int v = (i < n) ? cnt[i] : 0;
    s[threadIdx.x] = v;
    __syncthreads();
    for (int off = 1; off < 256; off <<= 1) {
        int t = (threadIdx.x >= off) ? s[threadIdx.x - off] : 0;
        __syncthreads();
        s[threadIdx.x] += t;
        __syncthreads();
    }
    if (i < n) rs[i] = s[threadIdx.x] - v;
    if (threadIdx.x == 255) bsum[blockIdx.x] = s[255];
}

__global__ void scanB_kernel(const int* __restrict__ bsum, int* __restrict__ boff, int nb) {
    __shared__ int s[512];
    int tid = threadIdx.x;
    int v = (tid < nb) ? bsum[tid] : 0;
    s[tid] = v;
    __syncthreads();
    for (int off = 1; off < 512; off <<= 1) {
        int t = (tid >= off) ? s[tid - off] : 0;
        __syncthreads();
        s[tid] += t;
        __syncthreads();
    }
    if (tid < nb) boff[tid] = s[tid] - v;
}

__global__ void scanC_kernel(int* __restrict__ rs, const int* __restrict__ boff,
                             int* __restrict__ cursor, const int* __restrict__ cnt,
                             float* __restrict__ dinv, int n) {
    int i = blockIdx.x * 256 + threadIdx.x;
    if (i < n) {
        int v = rs[i] + boff[blockIdx.x];
        rs[i] = v;
        cursor[i] = v;
        dinv[i] = 1.0f / sqrtf((float)cnt[i] + 1.0f);
    }
}

// pack (src, dinv[src]) per edge, dst-sorted
__global__ void scatter_kernel(const int* __restrict__ src, const int* __restrict__ dst,
                               int* __restrict__ cursor, const float* __restrict__ dinv,
                               int2* __restrict__ sedge, int E) {
    int e = blockIdx.x * 256 + threadIdx.x;
    if (e < E) {
        int d = dst[e];
        int s = src[e];
        int pos = atomicAdd(&cursor[d], 1);
        sedge[pos] = make_int2(s, __float_as_int(dinv[s]));
    }
}

// ---------------- MFMA GEMMs ----------------
// mfma_f32_16x16x32_bf16 layouts (guide-verified):
//   A: lane holds A[m = lane&15][k = (lane>>4)*8 + j], j=0..7
//   B: lane holds B[k = (lane>>4)*8 + j][n = lane&15]
//   C/D: col = lane&15, row = (lane>>4)*4 + reg

// GEMM1: h1[M,128] = x[M,256](fp32) @ W1[256,128](fp32), out bf16.
// Whole W1 staged once per block into LDS in fragment order (64 KB).
// A frags loaded global->reg with fused fp32->bf16 cvt. 4 waves, 32 rows each.
__global__ __launch_bounds__(256)
void gemm1_kernel(const float* __restrict__ A, const float* __restrict__ Bw,
                  ushort* __restrict__ C, int M, int nTiles) {
    __shared__ short8 BsF[8 * 8 * 64];   // [k0][nt][lane] = 64 KB
    int tid = threadIdx.x;
    int lane = tid & 63, w = tid >> 6;
    for (int f = tid; f < 4096; f += 256) {
        int k0 = f >> 9, nt = (f >> 6) & 7, ln = f & 63;
        int kbase = k0 * 32 + (ln >> 4) * 8;
        int n = nt * 16 + (ln & 15);
        short8 frag;
#pragma unroll
        for (int j = 0; j < 8; ++j) frag[j] = (short)bf16_rne(Bw[(kbase + j) * F_MID + n]);
        BsF[f] = frag;
    }
    __syncthreads();

    for (int t = blockIdx.x; t < nTiles; t += gridDim.x) {
        int m0 = t * 128 + w * 32;
        f32x4 acc[2][8];
#pragma unroll
        for (int mt = 0; mt < 2; ++mt)
#pragma unroll
            for (int nt = 0; nt < 8; ++nt) acc[mt][nt] = (f32x4){0.f, 0.f, 0.f, 0.f};

        for (int k0 = 0; k0 < 8; ++k0) {
            short8 afr[2];
#pragma unroll
            for (int mt = 0; mt < 2; ++mt) {
                int m = m0 + mt * 16 + (lane & 15);
                int k = k0 * 32 + (lane >> 4) * 8;
                short8 af = (short8){0, 0, 0, 0, 0, 0, 0, 0};
                if (m < M) {
                    float4 v0 = *(const float4*)&A[(size_t)m * F_IN + k];
                    float4 v1 = *(const float4*)&A[(size_t)m * F_IN + k + 4];
                    af[0] = (short)bf16_rne(v0.x); af[1] = (short)bf16_rne(v0.y);
                    af[2] = (short)bf16_rne(v0.z); af[3] = (short)bf16_rne(v0.w);
                    af[4] = (short)bf16_rne(v1.x); af[5] = (short)bf16_rne(v1.y);
                    af[6] = (short)bf16_rne(v1.z); af[7] = (short)bf16_rne(v1.w);
                }
                afr[mt] = af;
            }
#pragma unroll
            for (int nt = 0; nt < 8; ++nt) {
                short8 bfr = BsF[(k0 * 8 + nt) * 64 + lane];
                acc[0][nt] = __builtin_amdgcn_mfma_f32_16x16x32_bf16(afr[0], bfr, acc[0][nt], 0, 0, 0);
                acc[1][nt] = __builtin_amdgcn_mfma_f32_16x16x32_bf16(afr[1], bfr, acc[1][nt], 0, 0, 0);
            }
        }
#pragma unroll
        for (int mt = 0; mt < 2; ++mt)
#pragma unroll
            for (int nt = 0; nt < 8; ++nt)
#pragma unroll
                for (int i = 0; i < 4; ++i) {
                    int r = m0 + mt * 16 + (lane >> 4) * 4 + i;
                    if (r < M) C[(size_t)r * F_MID + nt * 16 + (lane & 15)] = bf16_rne(acc[mt][nt][i]);
                }
    }
}

// GEMM2: h2[M,64] = h1a[M,128](bf16) @ W2[128,64](fp32), out bf16.
__global__ __launch_bounds__(256)
void gemm2_kernel(const ushort* __restrict__ A, const float* __restrict__ Bw,
                  ushort* __restrict__ C, int M, int nTiles) {
    __shared__ short8 BsF[4 * 4 * 64];   // [k0][nt][lane] = 16 KB
    int tid = threadIdx.x;
    int lane = tid & 63, w = tid >> 6;
    for (int f = tid; f < 1024; f += 256) {
        int k0 = f >> 8, nt = (f >> 6) & 3, ln = f & 63;
        int kbase = k0 * 32 + (ln >> 4) * 8;
        int n = nt * 16 + (ln & 15);
        short8 frag;
#pragma unroll
        for (int j = 0; j < 8; ++j) frag[j] = (short)bf16_rne(Bw[(kbase + j) * F_OUT + n]);
        BsF[f] = frag;
    }
    __syncthreads();

    for (int t = blockIdx.x; t < nTiles; t += gridDim.x) {
        int m0 = t * 128 + w * 32;
        f32x4 acc[2][4];
#pragma unroll
        for (int mt = 0; mt < 2; ++mt)
#pragma unroll
            for (int nt = 0; nt < 4; ++nt) acc[mt][nt] = (f32x4){0.f, 0.f, 0.f, 0.f};

        for (int k0 = 0; k0 < 4; ++k0) {
            short8 afr[2];
#pragma unroll
            for (int mt = 0; mt < 2; ++mt) {
                int m = m0 + mt * 16 + (lane & 15);
                int k = k0 * 32 + (lane >> 4) * 8;
                short8 af = (short8){0, 0, 0, 0, 0, 0, 0, 0};
                if (m < M) af = *(const short8*)&A[(size_t)m * F_MID + k];
                afr[mt] = af;
            }
#pragma unroll
            for (int nt = 0; nt < 4; ++nt) {
                short8 bfr = BsF[(k0 * 4 + nt) * 64 + lane];
                acc[0][nt] = __builtin_amdgcn_mfma_f32_16x16x32_bf16(afr[0], bfr, acc[0][nt], 0, 0, 0);
                acc[1][nt] = __builtin_amdgcn_mfma_f32_16x16x32_bf16(afr[1], bfr, acc[1][nt], 0, 0, 0);
            }
        }
#pragma unroll
        for (int mt = 0; mt < 2; ++mt)
#pragma unroll
            for (int nt = 0; nt < 4; ++nt)
#pragma unroll
                for (int i = 0; i < 4; ++i) {
                    int r = m0 + mt * 16 + (lane >> 4) * 4 + i;
                    if (r < M) C[(size_t)r * F_OUT + nt * 16 + (lane & 15)] = bf16_rne(acc[mt][nt][i]);
                }
    }
}

// ---------------- aggregation ----------------
// agg1: h1(bf16,128) -> h1a(bf16,128), +self +bias +relu. One wave/node,
// lane handles cols {2l, 2l+1} packed in one uint; 64-edge shfl broadcast.
__global__ __launch_bounds__(256)
void agg1_kernel(const uint* __restrict__ h, const int* __restrict__ rs,
                 const int* __restrict__ cnt, const int2* __restrict__ sedge,
                 const float* __restrict__ dinv, const float* __restrict__ bias,
                 uint* __restrict__ outp, int n) {
    int w = threadIdx.x >> 6, l = threadIdx.x & 63;
    int node = blockIdx.x * 4 + w;
    if (node >= n) return;
    int start = rs[node], c = cnt[node];
    float dn = dinv[node];
    float ax = 0.f, ay = 0.f;
    for (int base = 0; base < c; base += 64) {
        int take = c - base;
        if (take > 64) take = 64;
        int2 e = (l < take) ? sedge[start + base + l] : make_int2(0, 0);
        for (int j = 0; j < take; ++j) {
            int s = __shfl(e.x, j);
            float ws = __int_as_float(__shfl(e.y, j));
            uint raw = h[(size_t)s * 64 + l];
            float fx = __uint_as_float(raw << 16);
            float fy = __uint_as_float(raw & 0xffff0000u);
            ax = fmaf(ws, fx, ax);
            ay = fmaf(ws, fy, ay);
        }
    }
    uint rawS = h[(size_t)node * 64 + l];
    float hx = __uint_as_float(rawS << 16);
    float hy = __uint_as_float(rawS & 0xffff0000u);
    float2 b = ((const float2*)bias)[l];
    float ox = fmaxf(fmaf(dn, ax, dn * dn * hx) + b.x, 0.f);
    float oy = fmaxf(fmaf(dn, ay, dn * dn * hy) + b.y, 0.f);
    outp[(size_t)node * 64 + l] = (uint)bf16_rne(ox) | ((uint)bf16_rne(oy) << 16);
}

// agg2: h2(bf16,64) -> out(fp32,64), +self +bias, fused log_softmax.
__global__ __launch_bounds__(256)
void agg2_kernel(const ushort* __restrict__ h, const int* __restrict__ rs,
                 const int* __restrict__ cnt, const int2* __restrict__ sedge,
                 const float* __restrict__ dinv, const float* __restrict__ bias,
                 float* __restrict__ out, int n) {
    int w = threadIdx.x >> 6, l = threadIdx.x & 63;
    int node = blockIdx.x * 4 + w;
    if (node >= n) return;
    int start = rs[node], c = cnt[node];
    float dn = dinv[node];
    float acc = 0.f;
    for (int base = 0; base < c; base += 64) {
        int take = c - base;
        if (take > 64) take = 64;
        int2 e = (l < take) ? sedge[start + base + l] : make_int2(0, 0);
        for (int j = 0; j < take; ++j) {
            int s = __shfl(e.x, j);
            float ws = __int_as_float(__shfl(e.y, j));
            acc = fmaf(ws, bf16_f(h[(size_t)s * 64 + l]), acc);
        }
    }
    float v = fmaf(dn, acc, dn * dn * bf16_f(h[(size_t)node * 64 + l])) + bias[l];
    float m = v;
    for (int off = 32; off; off >>= 1) m = fmaxf(m, __shfl_xor(m, off));
    float e = expf(v - m);
    float ssum = e;
    for (int off = 32; off; off >>= 1) ssum += __shfl_xor(ssum, off);
    out[(size_t)node * 64 + l] = v - m - logf(ssum);
}

// ---------------- launch ----------------

extern "C" void kernel_launch(void* const* d_in, const int* in_sizes, int n_in,
                              void* d_out, int out_size, void* d_ws, size_t ws_size,
                              hipStream_t stream) {
    const float* x  = (const float*)d_in[0];
    const int*   ei = (const int*)d_in[1];
    const float* W1 = (const float*)d_in[2];
    const float* b1 = (const float*)d_in[3];
    const float* W2 = (const float*)d_in[4];
    const float* b2 = (const float*)d_in[5];
    float* out = (float*)d_out;

    const int N = N_NODES;
    const int E = in_sizes[1] / 2;
    const int* src = ei;
    const int* dst = ei + E;

    char* ws = (char*)d_ws;
    size_t off = 0;
    auto alloc = [&](size_t bytes) {
        char* p = ws + off;
        off = (off + bytes + 255) & ~(size_t)255;
        return p;
    };
    int*   cnt    = (int*)alloc(N * 4);
    int*   rs     = (int*)alloc(N * 4);
    int*   cursor = (int*)alloc(N * 4);
    float* dinv   = (float*)alloc(N * 4);
    int*   bsum   = (int*)alloc(512 * 4);
    int*   boff   = (int*)alloc(512 * 4);
    int2*  sedge  = (int2*)alloc((size_t)E * 8);
    uint*  h1     = (uint*)alloc((size_t)N * 64 * 4);   // bf16 x2 packed, 128 cols
    uint*  h1a    = (uint*)alloc((size_t)N * 64 * 4);
    ushort* h2    = (ushort*)h1;                        // alias: h1 dead after agg1

    const int nScanBlocks = (N + 255) / 256;
    const int nEdgeBlocks = (E + 255) / 256;
    const int nAggBlocks  = (N + 3) / 4;
    const int nTiles      = (N + 127) / 128;            // 782
    const int nGemmGrid   = (nTiles + 1) / 2;           // 391, 2 tiles/block

    hipMemsetAsync(cnt, 0, N * 4, stream);

    hist_kernel<<<nEdgeBlocks, 256, 0, stream>>>(dst, cnt, E);
    scanA_kernel<<<nScanBlocks, 256, 0, stream>>>(cnt, rs, bsum, N);
    scanB_kernel<<<1, 512, 0, stream>>>(bsum, boff, nScanBlocks);
    scanC_kernel<<<nScanBlocks, 256, 0, stream>>>(rs, boff, cursor, cnt, dinv, N);
    scatter_kernel<<<nEdgeBlocks, 256, 0, stream>>>(src, dst, cursor, dinv, sedge, E);

    gemm1_kernel<<<nGemmGrid, 256, 0, stream>>>(x, W1, (ushort*)h1, N, nTiles);
    agg1_kernel<<<nAggBlocks, 256, 0, stream>>>(h1, rs, cnt, sedge, dinv, b1, h1a, N);
    gemm2_kernel<<<nGemmGrid, 256, 0, stream>>>((const ushort*)h1a, W2, h2, N, nTiles);
    agg2_kernel<<<nAggBlocks, 256, 0, stream>>>(h2, rs, cnt, sedge, dinv, b2, out, N);
}

// Round 3
// 550.763 us; speedup vs baseline: 1.4305x; 1.0682x over previous
//
#include <hip/hip_runtime.h>
#include <hip/hip_bf16.h>

// GCN 2-layer: out = log_softmax(GCN2(relu(GCN1(x))))
// Round 3: dinv pre-scaled into GEMM epilogues (edge list = bare int src),
// 4-edges-per-iteration quarter-wave gather aggregation, fragment-ordered
// weight prep kernel (gemm staging = 16 coalesced b128 loads).

#define N_NODES 100000
#define F_IN 256
#define F_MID 128
#define F_OUT 64

typedef __attribute__((ext_vector_type(8))) short short8;
typedef __attribute__((ext_vector_type(4))) float f32x4;

__device__ inline ushort bf16_rne(float f) {
    uint u = __float_as_uint(f);
    u += 0x7FFF + ((u >> 16) & 1);
    return (ushort)(u >> 16);
}
__device__ inline float lo16(uint r) { return __uint_as_float(r << 16); }
__device__ inline float hi16(uint r) { return __uint_as_float(r & 0xffff0000u); }
__device__ inline uint pack_bf2(float a, float b) {
    return (uint)bf16_rne(a) | ((uint)bf16_rne(b) << 16);
}

// ---------------- sort pipeline ----------------

__global__ void hist_kernel(const int* __restrict__ dst, int* __restrict__ cnt, int E) {
    int e = blockIdx.x * 256 + threadIdx.x;
    if (e < E) atomicAdd(&cnt[dst[e]], 1);
}

__global__ void scanA_kernel(const int* __restrict__ cnt, int* __restrict__ rs,
                             int* __restrict__ bsum, int n) {
    __shared__ int s[256];
    int i = blockIdx.x * 256 + threadIdx.x;
    int v = (i < n) ? cnt[i] : 0;
    s[threadIdx.x] = v;
    __syncthreads();
    for (int off = 1; off < 256; off <<= 1) {
        int t = (threadIdx.x >= off) ? s[threadIdx.x - off] : 0;
        __syncthreads();
        s[threadIdx.x] += t;
        __syncthreads();
    }
    if (i < n) rs[i] = s[threadIdx.x] - v;
    if (threadIdx.x == 255) bsum[blockIdx.x] = s[255];
}

__global__ void scanB_kernel(const int* __restrict__ bsum, int* __restrict__ boff, int nb) {
    __shared__ int s[512];
    int tid = threadIdx.x;
    int v = (tid < nb) ? bsum[tid] : 0;
    s[tid] = v;
    __syncthreads();
    for (int off = 1; off < 512; off <<= 1) {
        int t = (tid >= off) ? s[tid - off] : 0;
        __syncthreads();
        s[tid] += t;
        __syncthreads();
    }
    if (tid < nb) boff[tid] = s[tid] - v;
}

__global__ void scanC_kernel(int* __restrict__ rs, const int* __restrict__ boff,
                             int* __restrict__ cursor, const int* __restrict__ cnt,
                             float* __restrict__ dinv, int n) {
    int i = blockIdx.x * 256 + threadIdx.x;
    if (i < n) {
        int v = rs[i] + boff[blockIdx.x];
        rs[i] = v;
        cursor[i] = v;
        dinv[i] = 1.0f / sqrtf((float)cnt[i] + 1.0f);
    }
}

__global__ void scatter_kernel(const int* __restrict__ src, const int* __restrict__ dst,
                               int* __restrict__ cursor, int* __restrict__ ssrc, int E) {
    int e = blockIdx.x * 256 + threadIdx.x;
    if (e < E) {
        int d = dst[e];
        int pos = atomicAdd(&cursor[d], 1);
        ssrc[pos] = src[e];
    }
}

// ---------------- weight prep: fragment-ordered bf16 ----------------
// mfma_f32_16x16x32_bf16 B-frag: lane holds B[k=(lane>>4)*8+j][n=lane&15].
// blocks 0..15 -> W1f (4096 frags), 16..19 -> W2f (1024 frags)
__global__ __launch_bounds__(256)
void wprep_kernel(const float* __restrict__ W1, const float* __restrict__ W2,
                  short8* __restrict__ W1f, short8* __restrict__ W2f) {
    int b = blockIdx.x;
    if (b < 16) {
        int f = b * 256 + threadIdx.x;
        int k0 = f >> 9, nt = (f >> 6) & 7, ln = f & 63;
        int kbase = k0 * 32 + (ln >> 4) * 8;
        int n = nt * 16 + (ln & 15);
        short8 fr;
#pragma unroll
        for (int j = 0; j < 8; ++j) fr[j] = (short)bf16_rne(W1[(kbase + j) * F_MID + n]);
        W1f[f] = fr;
    } else {
        int f = (b - 16) * 256 + threadIdx.x;
        int k0 = f >> 8, nt = (f >> 6) & 3, ln = f & 63;
        int kbase = k0 * 32 + (ln >> 4) * 8;
        int n = nt * 16 + (ln & 15);
        short8 fr;
#pragma unroll
        for (int j = 0; j < 8; ++j) fr[j] = (short)bf16_rne(W2[(kbase + j) * F_OUT + n]);
        W2f[f] = fr;
    }
}

// ---------------- MFMA GEMMs ----------------
// A: lane holds A[m=lane&15][k=(lane>>4)*8+j]; C/D: col=lane&15, row=(lane>>4)*4+reg.

// h1s[M,128](bf16) = dinv[m] * (x[M,256](fp32) @ W1bf16)
__global__ __launch_bounds__(256)
void gemm1_kernel(const float* __restrict__ A, const short8* __restrict__ Wf,
                  const float* __restrict__ dinv, ushort* __restrict__ C,
                  int M, int nTiles) {
    __shared__ short8 BsF[4096];   // 64 KB
    int tid = threadIdx.x;
    int lane = tid & 63, w = tid >> 6;
    for (int f = tid; f < 4096; f += 256) BsF[f] = Wf[f];
    __syncthreads();

    for (int t = blockIdx.x; t < nTiles; t += gridDim.x) {
        int m0 = t * 128 + w * 32;
        f32x4 acc[2][8];
#pragma unroll
        for (int mt = 0; mt < 2; ++mt)
#pragma unroll
            for (int nt = 0; nt < 8; ++nt) acc[mt][nt] = (f32x4){0.f, 0.f, 0.f, 0.f};

        for (int k0 = 0; k0 < 8; ++k0) {
            short8 afr[2];
#pragma unroll
            for (int mt = 0; mt < 2; ++mt) {
                int m = m0 + mt * 16 + (lane & 15);
                int k = k0 * 32 + (lane >> 4) * 8;
                short8 af = (short8){0, 0, 0, 0, 0, 0, 0, 0};
                if (m < M) {
                    const float4* ap = (const float4*)&A[(size_t)m * F_IN + k];
                    float4 v0 = ap[0], v1 = ap[1];
                    af[0] = (short)bf16_rne(v0.x); af[1] = (short)bf16_rne(v0.y);
                    af[2] = (short)bf16_rne(v0.z); af[3] = (short)bf16_rne(v0.w);
                    af[4] = (short)bf16_rne(v1.x); af[5] = (short)bf16_rne(v1.y);
                    af[6] = (short)bf16_rne(v1.z); af[7] = (short)bf16_rne(v1.w);
                }
                afr[mt] = af;
            }
#pragma unroll
            for (int nt = 0; nt < 8; ++nt) {
                short8 bfr = BsF[(k0 * 8 + nt) * 64 + lane];
                acc[0][nt] = __builtin_amdgcn_mfma_f32_16x16x32_bf16(afr[0], bfr, acc[0][nt], 0, 0, 0);
                acc[1][nt] = __builtin_amdgcn_mfma_f32_16x16x32_bf16(afr[1], bfr, acc[1][nt], 0, 0, 0);
            }
        }
#pragma unroll
        for (int mt = 0; mt < 2; ++mt)
#pragma unroll
            for (int i = 0; i < 4; ++i) {
                int r = m0 + mt * 16 + (lane >> 4) * 4 + i;
                if (r < M) {
                    float dv = dinv[r];
#pragma unroll
                    for (int nt = 0; nt < 8; ++nt)
                        C[(size_t)r * F_MID + nt * 16 + (lane & 15)] = bf16_rne(dv * acc[mt][nt][i]);
                }
            }
    }
}

// h2s[M,64](bf16) = dinv[m] * (h1a[M,128](bf16) @ W2bf16)
__global__ __launch_bounds__(256)
void gemm2_kernel(const ushort* __restrict__ A, const short8* __restrict__ Wf,
                  const float* __restrict__ dinv, ushort* __restrict__ C,
                  int M, int nTiles) {
    __shared__ short8 BsF[1024];   // 16 KB
    int tid = threadIdx.x;
    int lane = tid & 63, w = tid >> 6;
    for (int f = tid; f < 1024; f += 256) BsF[f] = Wf[f];
    __syncthreads();

    for (int t = blockIdx.x; t < nTiles; t += gridDim.x) {
        int m0 = t * 128 + w * 32;
        f32x4 acc[2][4];
#pragma unroll
        for (int mt = 0; mt < 2; ++mt)
#pragma unroll
            for (int nt = 0; nt < 4; ++nt) acc[mt][nt] = (f32x4){0.f, 0.f, 0.f, 0.f};

        for (int k0 = 0; k0 < 4; ++k0) {
            short8 afr[2];
#pragma unroll
            for (int mt = 0; mt < 2; ++mt) {
                int m = m0 + mt * 16 + (lane & 15);
                int k = k0 * 32 + (lane >> 4) * 8;
                short8 af = (short8){0, 0, 0, 0, 0, 0, 0, 0};
                if (m < M) af = *(const short8*)&A[(size_t)m * F_MID + k];
                afr[mt] = af;
            }
#pragma unroll
            for (int nt = 0; nt < 4; ++nt) {
                short8 bfr = BsF[(k0 * 4 + nt) * 64 + lane];
                acc[0][nt] = __builtin_amdgcn_mfma_f32_16x16x32_bf16(afr[0], bfr, acc[0][nt], 0, 0, 0);
                acc[1][nt] = __builtin_amdgcn_mfma_f32_16x16x32_bf16(afr[1], bfr, acc[1][nt], 0, 0, 0);
            }
        }
#pragma unroll
        for (int mt = 0; mt < 2; ++mt)
#pragma unroll
            for (int i = 0; i < 4; ++i) {
                int r = m0 + mt * 16 + (lane >> 4) * 4 + i;
                if (r < M) {
                    float dv = dinv[r];
#pragma unroll
                    for (int nt = 0; nt < 4; ++nt)
                        C[(size_t)r * F_OUT + nt * 16 + (lane & 15)] = bf16_rne(dv * acc[mt][nt][i]);
                }
            }
    }
}

// ---------------- aggregation ----------------
// agg1: rows pre-scaled by dinv[src]. One wave/node; quarter q handles edge
// base+q; 16 lanes x uint4 (16B) cover the 256-B row; butterfly fold at end.
// out = relu(dn*(sum_edges + self) + bias), bf16.
__global__ __launch_bounds__(256)
void agg1_kernel(const uint4* __restrict__ h, const int* __restrict__ rs,
                 const int* __restrict__ cnt, const int* __restrict__ ssrc,
                 const float* __restrict__ dinv, const float* __restrict__ bias,
                 uint4* __restrict__ outp, int n) {
    int w = threadIdx.x >> 6, lane = threadIdx.x & 63;
    int node = blockIdx.x * 4 + w;
    if (node >= n) return;
    int q = lane >> 4, c16 = lane & 15;
    int start = rs[node], c = cnt[node];
    float dn = dinv[node];
    float a[8];
#pragma unroll
    for (int i = 0; i < 8; ++i) a[i] = 0.f;

    for (int base = 0; base < c; base += 4) {
        int eidx = base + q;
        if (eidx < c) {
            int s = ssrc[start + eidx];
            uint4 r = h[(size_t)s * 16 + c16];
            a[0] += lo16(r.x); a[1] += hi16(r.x);
            a[2] += lo16(r.y); a[3] += hi16(r.y);
            a[4] += lo16(r.z); a[5] += hi16(r.z);
            a[6] += lo16(r.w); a[7] += hi16(r.w);
        }
    }
#pragma unroll
    for (int i = 0; i < 8; ++i) {
        a[i] += __shfl_xor(a[i], 16);
        a[i] += __shfl_xor(a[i], 32);
    }
    uint4 sr = h[(size_t)node * 16 + c16];
    const float4* b4 = (const float4*)bias;
    float4 b0 = b4[c16 * 2], b1 = b4[c16 * 2 + 1];
    float o0 = fmaxf(fmaf(dn, a[0] + lo16(sr.x), b0.x), 0.f);
    float o1 = fmaxf(fmaf(dn, a[1] + hi16(sr.x), b0.y), 0.f);
    float o2 = fmaxf(fmaf(dn, a[2] + lo16(sr.y), b0.z), 0.f);
    float o3 = fmaxf(fmaf(dn, a[3] + hi16(sr.y), b0.w), 0.f);
    float o4 = fmaxf(fmaf(dn, a[4] + lo16(sr.z), b1.x), 0.f);
    float o5 = fmaxf(fmaf(dn, a[5] + hi16(sr.z), b1.y), 0.f);
    float o6 = fmaxf(fmaf(dn, a[6] + lo16(sr.w), b1.z), 0.f);
    float o7 = fmaxf(fmaf(dn, a[7] + hi16(sr.w), b1.w), 0.f);
    if (q == 0) {
        uint4 ov;
        ov.x = pack_bf2(o0, o1);
        ov.y = pack_bf2(o2, o3);
        ov.z = pack_bf2(o4, o5);
        ov.w = pack_bf2(o6, o7);
        outp[(size_t)node * 16 + c16] = ov;
    }
}

// agg2: 64-col bf16 rows (128 B), 16 lanes x uint2; fused bias + log_softmax.
__global__ __launch_bounds__(256)
void agg2_kernel(const uint2* __restrict__ h, const int* __restrict__ rs,
                 const int* __restrict__ cnt, const int* __restrict__ ssrc,
                 const float* __restrict__ dinv, const float* __restrict__ bias,
                 float4* __restrict__ out4, int n) {
    int w = threadIdx.x >> 6, lane = threadIdx.x & 63;
    int node = blockIdx.x * 4 + w;
    if (node >= n) return;
    int q = lane >> 4, c16 = lane & 15;
    int start = rs[node], c = cnt[node];
    float dn = dinv[node];
    float a[4];
#pragma unroll
    for (int i = 0; i < 4; ++i) a[i] = 0.f;

    for (int base = 0; base < c; base += 4) {
        int eidx = base + q;
        if (eidx < c) {
            int s = ssrc[start + eidx];
            uint2 r = h[(size_t)s * 16 + c16];
            a[0] += lo16(r.x); a[1] += hi16(r.x);
            a[2] += lo16(r.y); a[3] += hi16(r.y);
        }
    }
#pragma unroll
    for (int i = 0; i < 4; ++i) {
        a[i] += __shfl_xor(a[i], 16);
        a[i] += __shfl_xor(a[i], 32);
    }
    uint2 sr = h[(size_t)node * 16 + c16];
    float4 bv = ((const float4*)bias)[c16];
    float v0 = fmaf(dn, a[0] + lo16(sr.x), bv.x);
    float v1 = fmaf(dn, a[1] + hi16(sr.x), bv.y);
    float v2 = fmaf(dn, a[2] + lo16(sr.y), bv.z);
    float v3 = fmaf(dn, a[3] + hi16(sr.y), bv.w);
    // log_softmax over 64 cols (4 per lane x 16 lanes, replicated per quarter)
    float m = fmaxf(fmaxf(v0, v1), fmaxf(v2, v3));
#pragma unroll
    for (int off = 1; off < 16; off <<= 1) m = fmaxf(m, __shfl_xor(m, off));
    float ssum = expf(v0 - m) + expf(v1 - m) + expf(v2 - m) + expf(v3 - m);
#pragma unroll
    for (int off = 1; off < 16; off <<= 1) ssum += __shfl_xor(ssum, off);
    float lg = m + logf(ssum);
    if (q == 0) out4[(size_t)node * 16 + c16] = make_float4(v0 - lg, v1 - lg, v2 - lg, v3 - lg);
}

// ---------------- launch ----------------

extern "C" void kernel_launch(void* const* d_in, const int* in_sizes, int n_in,
                              void* d_out, int out_size, void* d_ws, size_t ws_size,
                              hipStream_t stream) {
    const float* x  = (const float*)d_in[0];
    const int*   ei = (const int*)d_in[1];
    const float* W1 = (const float*)d_in[2];
    const float* b1 = (const float*)d_in[3];
    const float* W2 = (const float*)d_in[4];
    const float* b2 = (const float*)d_in[5];
    float* out = (float*)d_out;

    const int N = N_NODES;
    const int E = in_sizes[1] / 2;
    const int* src = ei;
    const int* dst = ei + E;

    char* ws = (char*)d_ws;
    size_t off = 0;
    auto alloc = [&](size_t bytes) {
        char* p = ws + off;
        off = (off + bytes + 255) & ~(size_t)255;
        return p;
    };
    int*    cnt    = (int*)alloc(N * 4);
    int*    rs     = (int*)alloc(N * 4);
    int*    cursor = (int*)alloc(N * 4);
    float*  dinv   = (float*)alloc(N * 4);
    int*    bsum   = (int*)alloc(512 * 4);
    int*    boff   = (int*)alloc(512 * 4);
    short8* W1f    = (short8*)alloc(4096 * 16);
    short8* W2f    = (short8*)alloc(1024 * 16);
    int*    ssrc   = (int*)alloc((size_t)E * 4);
    uint*   h1     = (uint*)alloc((size_t)N * 64 * 4);   // 128 bf16/row
    uint*   h1a    = (uint*)alloc((size_t)N * 64 * 4);
    ushort* h2     = (ushort*)h1;                        // alias: h1 dead after agg1

    const int nScanBlocks = (N + 255) / 256;
    const int nEdgeBlocks = (E + 255) / 256;
    const int nAggBlocks  = (N + 3) / 4;
    const int nTiles      = (N + 127) / 128;             // 782
    const int nGemmGrid   = 512;

    wprep_kernel<<<20, 256, 0, stream>>>(W1, W2, W1f, W2f);
    hipMemsetAsync(cnt, 0, N * 4, stream);

    hist_kernel<<<nEdgeBlocks, 256, 0, stream>>>(dst, cnt, E);
    scanA_kernel<<<nScanBlocks, 256, 0, stream>>>(cnt, rs, bsum, N);
    scanB_kernel<<<1, 512, 0, stream>>>(bsum, boff, nScanBlocks);
    scanC_kernel<<<nScanBlocks, 256, 0, stream>>>(rs, boff, cursor, cnt, dinv, N);
    scatter_kernel<<<nEdgeBlocks, 256, 0, stream>>>(src, dst, cursor, ssrc, E);

    gemm1_kernel<<<nGemmGrid, 256, 0, stream>>>(x, W1f, dinv, (ushort*)h1, N, nTiles);
    agg1_kernel<<<nAggBlocks, 256, 0, stream>>>((const uint4*)h1, rs, cnt, ssrc, dinv, b1,
                                                (uint4*)h1a, N);
    gemm2_kernel<<<nGemmGrid, 256, 0, stream>>>((const ushort*)h1a, W2f, dinv, h2, N, nTiles);
    agg2_kernel<<<nAggBlocks, 256, 0, stream>>>((const uint2*)h2, rs, cnt, ssrc, dinv, b2,
                                                (float4*)out, N);
}